// Round 7
// baseline (1694.920 us; speedup 1.0000x reference)
//
#include <hip/hip_runtime.h>

#define MNODES 50000
#define M_PAD  50048          // 391 * 128
#define NEDGES 800000
#define DIN    128
#define DD     256
#define D2     512
#define NLAYERS 3
#define BN_EPS 1e-5f
#define NBUCK  196            // ceil(50000/256)

typedef unsigned short ushort_t;
typedef __bf16 v8bf __attribute__((ext_vector_type(8)));
typedef float  v4f  __attribute__((ext_vector_type(4)));

#define GLOBAL_AS __attribute__((address_space(1)))
#define LDS_AS    __attribute__((address_space(3)))

__device__ __forceinline__ float bf2f(ushort_t u) {
    unsigned x = ((unsigned)u) << 16;
    return __uint_as_float(x);
}
__device__ __forceinline__ ushort_t f2bf(float f) {
    unsigned u = __float_as_uint(f);
    u += 0x7FFF + ((u >> 16) & 1);   // RNE
    return (ushort_t)(u >> 16);
}
__device__ __forceinline__ void async16(const ushort_t* g, ushort_t* l) {
    __builtin_amdgcn_global_load_lds((const GLOBAL_AS unsigned int*)g,
                                     (LDS_AS unsigned int*)l, 16, 0, 0);
}
#define BARRIER() asm volatile("s_barrier" ::: "memory")
#define VMWAIT4() asm volatile("s_waitcnt vmcnt(4)" ::: "memory")
#define VMWAIT0() asm volatile("s_waitcnt vmcnt(0)" ::: "memory")

// ---------------- fused prep ----------------
#define R0 (M_PAD * DIN)                       // 6406144
#define RW (DIN * DD + 2 * NLAYERS * DD * D2)  // 819200
__global__ void k_prep_all(const float* __restrict__ pre, ushort_t* __restrict__ preb,
                           const float* __restrict__ W0, const float* __restrict__ W1,
                           const float* __restrict__ W2,
                           ushort_t* __restrict__ W0T, ushort_t* __restrict__ W1T,
                           ushort_t* __restrict__ W2T,
                           float* __restrict__ caf, float* __restrict__ ccf,
                           float* __restrict__ sums1, float* __restrict__ sumsF,
                           int* __restrict__ bcnt) {
    int i = blockIdx.x * blockDim.x + threadIdx.x;
    if (i < R0) {
        int row = i >> 7;
        preb[i] = f2bf(row < MNODES ? pre[i] : 0.f);
        return;
    }
    int j = i - R0;
    if (j < RW) {
        if (j < DIN * DD) {
            int n = j >> 7, k = j & 127;
            W0T[j] = f2bf(W0[k * DD + n]);
        } else if (j < DIN * DD + NLAYERS * DD * D2) {
            int j2 = j - DIN * DD;
            int l = j2 >> 17, off = j2 & 131071;
            int n = off >> 8, k = off & 255;      // K=256, N=512
            W1T[(size_t)l * 131072 + off] = f2bf(W1[(size_t)l * 131072 + k * D2 + n]);
        } else {
            int j2 = j - DIN * DD - NLAYERS * DD * D2;
            int l = j2 >> 17, off = j2 & 131071;
            int n = off >> 9, k = off & 511;      // K=512, N=256
            W2T[(size_t)l * 131072 + off] = f2bf(W2[(size_t)l * 131072 + k * DD + n]);
        }
        return;
    }
    j -= RW;
    if (j < 256) { caf[j] = 1.f; ccf[j] = 0.f; return; }
    j -= 256;
    if (j < 1024) { sums1[j] = 0.f; return; }
    j -= 1024;
    if (j < 512) { sumsF[j] = 0.f; return; }
    j -= 512;
    if (j < 256) bcnt[j] = 0;
}

// ---------------- bucketed CSR build ----------------
// A: count edges per coarse bucket (dst>>8)
__global__ void k_bktA(const int* __restrict__ ei, int* __restrict__ bcnt) {
    int e = blockIdx.x * blockDim.x + threadIdx.x;
    if (e < NEDGES) atomicAdd(&bcnt[ei[e * 2 + 1] >> 8], 1);
}
// B: scan 196 bucket counts -> bbase (exclusive, incl. sentinel), bcur copy
__global__ __launch_bounds__(256)
void k_bktB(const int* __restrict__ bcnt, int* __restrict__ bbase,
            int* __restrict__ bcur) {
    __shared__ int tmp[256];
    int tid = threadIdx.x;
    int v = (tid < NBUCK) ? bcnt[tid] : 0;
    tmp[tid] = v;
    __syncthreads();
    #pragma unroll
    for (int off = 1; off < 256; off <<= 1) {
        int t = (tid >= off) ? tmp[tid - off] : 0;
        __syncthreads();
        tmp[tid] += t;
        __syncthreads();
    }
    int excl = tmp[tid] - v;
    if (tid <= NBUCK) bbase[tid] = excl;
    if (tid < NBUCK) bcur[tid] = excl;
}
// C: scatter packed (src | dstlow<<16) into bucket regions (sequential/bucket)
__global__ void k_bktC(const int* __restrict__ ei, int* __restrict__ bcur,
                       unsigned* __restrict__ ebuf) {
    int e = blockIdx.x * blockDim.x + threadIdx.x;
    if (e < NEDGES) {
        int src = ei[e * 2], dst = ei[e * 2 + 1];
        int pos = atomicAdd(&bcur[dst >> 8], 1);
        ebuf[pos] = (unsigned)src | ((unsigned)(dst & 255) << 16);
    }
}
// D: per-bucket local CSR: count -> scan -> rowptr -> cursor-fill col
__global__ __launch_bounds__(256)
void k_bktD(const unsigned* __restrict__ ebuf, const int* __restrict__ bbase,
            int* __restrict__ rowptr, int* __restrict__ col) {
    __shared__ int scnt[256];
    __shared__ int sscan[256];
    int b = blockIdx.x;
    int tid = threadIdx.x;
    int s = bbase[b], e = bbase[b + 1];
    scnt[tid] = 0;
    __syncthreads();
    for (int i = s + tid; i < e; i += 256)
        atomicAdd(&scnt[ebuf[i] >> 16], 1);
    __syncthreads();
    int v = scnt[tid];
    sscan[tid] = v;
    __syncthreads();
    #pragma unroll
    for (int off = 1; off < 256; off <<= 1) {
        int t = (tid >= off) ? sscan[tid - off] : 0;
        __syncthreads();
        sscan[tid] += t;
        __syncthreads();
    }
    int excl = sscan[tid] - v;
    int gnode = b * 256 + tid;
    if (gnode <= MNODES) rowptr[gnode] = s + excl;
    if (b == NBUCK - 1 && tid == 255) rowptr[MNODES] = e;  // safety (gnode 50000 covered at tid 80)
    __syncthreads();
    scnt[tid] = excl;          // becomes cursor
    __syncthreads();
    for (int i = s + tid; i < e; i += 256) {
        unsigned u = ebuf[i];
        int pos = s + atomicAdd(&scnt[u >> 16], 1);
        col[pos] = (int)(u & 0xFFFF);
    }
}

// ---------------- gather: out = ca*(x[n] + sum x[src]) + (deg+1)*cc ----------
__global__ void k_gather(const int* __restrict__ rowptr, const int* __restrict__ col,
                         const ushort_t* __restrict__ x, const float* __restrict__ ca,
                         const float* __restrict__ cc, ushort_t* __restrict__ out) {
    int node = blockIdx.x * 4 + (threadIdx.x >> 6);
    int lane = threadIdx.x & 63;
    if (node >= MNODES) return;
    const ushort4* xp = (const ushort4*)x;
    ushort4 v = xp[(size_t)node * 64 + lane];
    float a0 = bf2f(v.x), a1 = bf2f(v.y), a2 = bf2f(v.z), a3 = bf2f(v.w);
    int s = rowptr[node], e = rowptr[node + 1];
    int i = s;
    for (; i + 7 < e; i += 8) {
        ushort4 u[8];
        #pragma unroll
        for (int j = 0; j < 8; j++) u[j] = xp[(size_t)col[i + j] * 64 + lane];
        #pragma unroll
        for (int j = 0; j < 8; j++) {
            a0 += bf2f(u[j].x); a1 += bf2f(u[j].y);
            a2 += bf2f(u[j].z); a3 += bf2f(u[j].w);
        }
    }
    for (; i < e; i++) {
        ushort4 u = xp[(size_t)col[i] * 64 + lane];
        a0 += bf2f(u.x); a1 += bf2f(u.y); a2 += bf2f(u.z); a3 += bf2f(u.w);
    }
    int c = lane * 4;
    float dn = (float)(e - s) + 1.0f;
    ushort4 o;
    o.x = f2bf(ca[c + 0] * a0 + dn * cc[c + 0]);
    o.y = f2bf(ca[c + 1] * a1 + dn * cc[c + 1]);
    o.z = f2bf(ca[c + 2] * a2 + dn * cc[c + 2]);
    o.w = f2bf(ca[c + 3] * a3 + dn * cc[c + 3]);
    ((ushort4*)out)[(size_t)node * 64 + lane] = o;
}

// ---------------- BN coeffs (re-zeros stats) ----------------
__global__ void k_coeffs(float* __restrict__ sums, float* __restrict__ sumsq,
                         const float* __restrict__ g, const float* __restrict__ beta,
                         float* __restrict__ ca, float* __restrict__ cc, int n) {
    int c = blockIdx.x * blockDim.x + threadIdx.x;
    if (c >= n) return;
    float mean = sums[c] * (1.0f / MNODES);
    float var  = sumsq[c] * (1.0f / MNODES) - mean * mean;
    float a    = g[c] * rsqrtf(var + BN_EPS);
    ca[c] = a;
    cc[c] = beta[c] - a * mean;
    sums[c] = 0.f;
    sumsq[c] = 0.f;
}

// ---------------- h = relu(ca*h + cc), in place, bf16, 512 cols --------------
__global__ void k_prerelu(ushort_t* __restrict__ h, const float* __restrict__ ca,
                          const float* __restrict__ cc) {
    int i = blockIdx.x * blockDim.x + threadIdx.x;
    if (i >= MNODES * (D2 / 4)) return;
    int c = (i * 4) & (D2 - 1);
    ushort4 v = ((const ushort4*)h)[i];
    ushort4 o;
    o.x = f2bf(fmaxf(ca[c + 0] * bf2f(v.x) + cc[c + 0], 0.f));
    o.y = f2bf(fmaxf(ca[c + 1] * bf2f(v.y) + cc[c + 1], 0.f));
    o.z = f2bf(fmaxf(ca[c + 2] * bf2f(v.z) + cc[c + 2], 0.f));
    o.w = f2bf(fmaxf(ca[c + 3] * bf2f(v.w) + cc[c + 3], 0.f));
    ((ushort4*)h)[i] = o;
}

// ---------------- final: d_out = ca*h + cc (fp32) ----------------
__global__ void k_apply_out(const ushort_t* __restrict__ h, const float* __restrict__ ca,
                            const float* __restrict__ cc, float* __restrict__ out) {
    int i = blockIdx.x * blockDim.x + threadIdx.x;
    if (i >= MNODES * 64) return;
    int c = (i & 63) * 4;
    ushort4 v = ((const ushort4*)h)[i];
    float4 o;
    o.x = ca[c + 0] * bf2f(v.x) + cc[c + 0];
    o.y = ca[c + 1] * bf2f(v.y) + cc[c + 1];
    o.z = ca[c + 2] * bf2f(v.z) + cc[c + 2];
    o.w = ca[c + 3] * bf2f(v.w) + cc[c + 3];
    ((float4*)out)[i] = o;
}

// ---------------- pipelined bf16 MFMA GEMM, 128x128 tile, BK=32 --------------
// DMA staging, double-buffered LDS (32 KB), raw s_barrier + vmcnt(4) pipeline.
// LDS row = 32 ushort (64 B), 4 chunks of 8; slot s of row r holds global
// chunk s ^ ((r>>1)&3): every consecutive 8-lane fragment-read group covers
// all 8 distinct 16B bank regions (4 slots x 2 row parities) -> conflict-free.
template<int DO_STATS, int RES>
__global__ __launch_bounds__(256, 5)
void k_gemm_bf(const ushort_t* __restrict__ A, const ushort_t* __restrict__ WT,
               const float* __restrict__ bias,
               const ushort_t* resid, const float* __restrict__ r_ca,
               const float* __restrict__ r_cc,
               ushort_t* out, float* __restrict__ sums, float* __restrict__ sumsq,
               int M, int K, int N) {
    __shared__ __align__(16) ushort_t As[2][128 * 32];
    __shared__ __align__(16) ushort_t Bs[2][128 * 32];
    const int tid = threadIdx.x;
    const int w = tid >> 6, lane = tid & 63;
    const int wm = w >> 1, wn = w & 1;
    const int quad = lane >> 4, l15 = lane & 15;
    const int m0 = blockIdx.y * 128, n0 = blockIdx.x * 128;

    // staging: lane i covers row ii*16+(i>>2), slot i&3, global chunk
    // (i&3) ^ ((row>>1)&3) = (i&3) ^ ((i>>3)&3)
    const ushort_t* aA[2];
    const ushort_t* aB[2];
    int aoff[2];
    #pragma unroll
    for (int j = 0; j < 2; j++) {
        int ii = j * 4 + w;
        int r = ii * 16 + (lane >> 2);
        int cg = (lane & 3) ^ ((lane >> 3) & 3);
        aA[j] = A  + (size_t)(m0 + r) * K + cg * 8;
        aB[j] = WT + (size_t)(n0 + r) * K + cg * 8;
        aoff[j] = ii * 512;
    }

    v4f acc[4][4];
    #pragma unroll
    for (int i = 0; i < 4; i++)
        #pragma unroll
        for (int j = 0; j < 4; j++)
            acc[i][j] = (v4f){0.f, 0.f, 0.f, 0.f};

    const int nk = K >> 5;

    #pragma unroll
    for (int j = 0; j < 2; j++) {
        async16(aA[j], &As[0][aoff[j]]);
        async16(aB[j], &Bs[0][aoff[j]]);
    }
    #pragma unroll
    for (int j = 0; j < 2; j++) {
        async16(aA[j] + 32, &As[1][aoff[j]]);
        async16(aB[j] + 32, &Bs[1][aoff[j]]);
    }
    VMWAIT4();
    BARRIER();

    const int sl = quad ^ ((l15 >> 1) & 3);
    for (int t = 0; t < nk; t++) {
        const ushort_t* Ab = As[t & 1];
        const ushort_t* Bb = Bs[t & 1];
        v8bf af[4], bfr[4];
        #pragma unroll
        for (int tt = 0; tt < 4; tt++) {
            int m_l = wm * 64 + tt * 16 + l15;
            af[tt]  = *(const v8bf*)&Ab[m_l * 32 + sl * 8];
            int n_l = wn * 64 + tt * 16 + l15;
            bfr[tt] = *(const v8bf*)&Bb[n_l * 32 + sl * 8];
        }
        #pragma unroll
        for (int mt = 0; mt < 4; mt++)
            #pragma unroll
            for (int nt = 0; nt < 4; nt++)
                acc[mt][nt] = __builtin_amdgcn_mfma_f32_16x16x32_bf16(
                    af[mt], bfr[nt], acc[mt][nt], 0, 0, 0);
        if (t == nk - 1) break;
        BARRIER();
        if (t + 2 < nk) {
            int kl = (t + 2) * 32;
            #pragma unroll
            for (int j = 0; j < 2; j++) {
                async16(aA[j] + kl, &As[t & 1][aoff[j]]);
                async16(aB[j] + kl, &Bs[t & 1][aoff[j]]);
            }
            VMWAIT4();
        } else {
            VMWAIT0();
        }
        BARRIER();
    }

    const int mlim = M - m0;
    float s_sum[4] = {0.f, 0.f, 0.f, 0.f}, s_sq[4] = {0.f, 0.f, 0.f, 0.f};
    #pragma unroll
    for (int nt = 0; nt < 4; nt++) {
        int colg = n0 + wn * 64 + nt * 16 + l15;
        float bia = bias[colg];
        float rca = 0.f, rcc = 0.f;
        if (RES) { rca = r_ca[colg]; rcc = r_cc[colg]; }
        #pragma unroll
        for (int mt = 0; mt < 4; mt++) {
            int rbase = wm * 64 + mt * 16 + quad * 4;
            #pragma unroll
            for (int r = 0; r < 4; r++) {
                int rl = rbase + r;
                if (rl < mlim) {
                    size_t idx = (size_t)(m0 + rl) * N + colg;
                    float v = acc[mt][nt][r] + bia;
                    if (RES) v += rca * bf2f(resid[idx]) + rcc;
                    out[idx] = f2bf(v);
                    if (DO_STATS) { s_sum[nt] += v; s_sq[nt] += v * v; }
                }
            }
        }
    }
    if (DO_STATS) {
        #pragma unroll
        for (int nt = 0; nt < 4; nt++) {
            float s = s_sum[nt], q = s_sq[nt];
            s += __shfl_xor(s, 16); q += __shfl_xor(q, 16);
            s += __shfl_xor(s, 32); q += __shfl_xor(q, 32);
            if (quad == 0) {
                int colg = n0 + wn * 64 + nt * 16 + l15;
                atomicAdd(&sums[colg], s);
                atomicAdd(&sumsq[colg], q);
            }
        }
    }
}

extern "C" void kernel_launch(void* const* d_in, const int* in_sizes, int n_in,
                              void* d_out, int out_size, void* d_ws, size_t ws_size,
                              hipStream_t stream) {
    const float* pre   = (const float*)d_in[0];
    const int*   ei    = (const int*)d_in[1];
    const float* W0    = (const float*)d_in[2];
    const float* b0    = (const float*)d_in[3];
    const float* W1    = (const float*)d_in[4];
    const float* b1    = (const float*)d_in[5];
    const float* g1    = (const float*)d_in[6];
    const float* beta1 = (const float*)d_in[7];
    const float* W2    = (const float*)d_in[8];
    const float* b2    = (const float*)d_in[9];
    const float* gf    = (const float*)d_in[10];
    const float* betaf = (const float*)d_in[11];

    char* p = (char*)d_ws;
    ushort_t* preb = (ushort_t*)p; p += (size_t)M_PAD * DIN * 2;
    ushort_t* ACT1 = (ushort_t*)p; p += (size_t)M_PAD * DD * 2;
    ushort_t* ACT2 = (ushort_t*)p; p += (size_t)M_PAD * DD * 2;
    ushort_t* H1   = (ushort_t*)p; p += (size_t)M_PAD * D2 * 2;
    ushort_t* W0T  = (ushort_t*)p; p += (size_t)DIN * DD * 2;
    ushort_t* W1T  = (ushort_t*)p; p += (size_t)NLAYERS * DD * D2 * 2;
    ushort_t* W2T  = (ushort_t*)p; p += (size_t)NLAYERS * D2 * DD * 2;
    float* sums1  = (float*)p; p += D2 * 4;
    float* sumsq1 = (float*)p; p += D2 * 4;
    float* ca1    = (float*)p; p += D2 * 4;
    float* cc1    = (float*)p; p += D2 * 4;
    float* sumsF  = (float*)p; p += DD * 4;
    float* sumsqF = (float*)p; p += DD * 4;
    float* caf    = (float*)p; p += DD * 4;
    float* ccf    = (float*)p; p += DD * 4;
    int* bcnt   = (int*)p; p += 256 * 4;
    int* bbase  = (int*)p; p += 256 * 4;
    int* bcur   = (int*)p; p += 256 * 4;
    int* rowptr = (int*)p; p += (size_t)(MNODES + 1) * 4;
    int* colx   = (int*)p; p += (size_t)NEDGES * 4;
    unsigned* ebuf = (unsigned*)p; p += (size_t)NEDGES * 4;

    dim3 blk(256);
    const int mb = (MNODES + 127) / 128;        // 391
    const int neb = (NEDGES + 255) / 256;       // 3125

    const int prep_total = R0 + RW + 256 + 1024 + 512 + 256;
    k_prep_all<<<(prep_total + 255) / 256, blk, 0, stream>>>(
        pre, preb, W0, W1, W2, W0T, W1T, W2T, caf, ccf, sums1, sumsF, bcnt);

    // bucketed CSR build
    k_bktA<<<neb, blk, 0, stream>>>(ei, bcnt);
    k_bktB<<<1, blk, 0, stream>>>(bcnt, bbase, bcur);
    k_bktC<<<neb, blk, 0, stream>>>(ei, bcur, ebuf);
    k_bktD<<<NBUCK, blk, 0, stream>>>(ebuf, bbase, rowptr, colx);

    // X0 = pre @ W0 + b0  -> ACT2
    k_gemm_bf<0, 0><<<dim3(DD / 128, mb), blk, 0, stream>>>(
        preb, W0T, b0, nullptr, nullptr, nullptr,
        ACT2, nullptr, nullptr, MNODES, DIN, DD);

    for (int l = 0; l < NLAYERS; l++) {
        // ACT1 = caf*(ACT2[n] + sum ACT2[src]) + (deg+1)*ccf
        k_gather<<<(MNODES + 3) / 4, blk, 0, stream>>>(rowptr, colx, ACT2, caf, ccf, ACT1);

        // H1 = ACT1 @ W1 + b1, fused column stats
        k_gemm_bf<1, 0><<<dim3(D2 / 128, mb), blk, 0, stream>>>(
            ACT1, W1T + (size_t)l * DD * D2, b1 + (size_t)l * D2,
            nullptr, nullptr, nullptr,
            H1, sums1, sumsq1, MNODES, DD, D2);
        k_coeffs<<<2, blk, 0, stream>>>(sums1, sumsq1, g1 + (size_t)l * D2,
                                        beta1 + (size_t)l * D2, ca1, cc1, D2);

        // H1 = relu(bn1(H1)) in place
        k_prerelu<<<(MNODES * (D2 / 4) + 255) / 256, blk, 0, stream>>>(H1, ca1, cc1);

        // ACT2 = H1 @ W2 + b2 + bn_prev(ACT2)  (in place; fused stats)
        k_gemm_bf<1, 1><<<dim3(DD / 128, mb), blk, 0, stream>>>(
            H1, W2T + (size_t)l * D2 * DD, b2 + (size_t)l * DD,
            ACT2, caf, ccf,
            ACT2, sumsF, sumsqF, MNODES, D2, DD);
        k_coeffs<<<1, blk, 0, stream>>>(sumsF, sumsqF, gf + (size_t)l * DD,
                                        betaf + (size_t)l * DD, caf, ccf, DD);
    }

    // d_out = caf*ACT2 + ccf  (fp32)
    k_apply_out<<<(MNODES * 64 + 255) / 256, blk, 0, stream>>>(ACT2, caf, ccf, (float*)d_out);
}

// Round 8
// 816.925 us; speedup vs baseline: 2.0748x; 2.0748x over previous
//
#include <hip/hip_runtime.h>

#define MNODES 50000
#define M_PAD  50048          // 391 * 128
#define NEDGES 800000
#define DIN    128
#define DD     256
#define D2     512
#define NLAYERS 3
#define BN_EPS 1e-5f
#define NBUCK  196            // ceil(50000/256)
#define CSRB   256            // blocks for bucketed CSR passes
#define EPB    ((NEDGES + CSRB - 1) / CSRB)   // 3125 edges/block

typedef unsigned short ushort_t;
typedef __bf16 v8bf __attribute__((ext_vector_type(8)));
typedef float  v4f  __attribute__((ext_vector_type(4)));

#define GLOBAL_AS __attribute__((address_space(1)))
#define LDS_AS    __attribute__((address_space(3)))

__device__ __forceinline__ float bf2f(ushort_t u) {
    unsigned x = ((unsigned)u) << 16;
    return __uint_as_float(x);
}
__device__ __forceinline__ ushort_t f2bf(float f) {
    unsigned u = __float_as_uint(f);
    u += 0x7FFF + ((u >> 16) & 1);   // RNE
    return (ushort_t)(u >> 16);
}
__device__ __forceinline__ void async16(const ushort_t* g, ushort_t* l) {
    __builtin_amdgcn_global_load_lds((const GLOBAL_AS unsigned int*)g,
                                     (LDS_AS unsigned int*)l, 16, 0, 0);
}
#define BARRIER() asm volatile("s_barrier" ::: "memory")
#define VMWAIT4() asm volatile("s_waitcnt vmcnt(4)" ::: "memory")
#define VMWAIT0() asm volatile("s_waitcnt vmcnt(0)" ::: "memory")

// ---------------- fused prep ----------------
#define R0 (M_PAD * DIN)                       // 6406144
#define RW (DIN * DD + 2 * NLAYERS * DD * D2)  // 819200
__global__ void k_prep_all(const float* __restrict__ pre, ushort_t* __restrict__ preb,
                           const float* __restrict__ W0, const float* __restrict__ W1,
                           const float* __restrict__ W2,
                           ushort_t* __restrict__ W0T, ushort_t* __restrict__ W1T,
                           ushort_t* __restrict__ W2T,
                           float* __restrict__ caf, float* __restrict__ ccf,
                           float* __restrict__ sums1, float* __restrict__ sumsF,
                           int* __restrict__ bcnt) {
    int i = blockIdx.x * blockDim.x + threadIdx.x;
    if (i < R0) {
        int row = i >> 7;
        preb[i] = f2bf(row < MNODES ? pre[i] : 0.f);
        return;
    }
    int j = i - R0;
    if (j < RW) {
        if (j < DIN * DD) {
            int n = j >> 7, k = j & 127;
            W0T[j] = f2bf(W0[k * DD + n]);
        } else if (j < DIN * DD + NLAYERS * DD * D2) {
            int j2 = j - DIN * DD;
            int l = j2 >> 17, off = j2 & 131071;
            int n = off >> 8, k = off & 255;      // K=256, N=512
            W1T[(size_t)l * 131072 + off] = f2bf(W1[(size_t)l * 131072 + k * D2 + n]);
        } else {
            int j2 = j - DIN * DD - NLAYERS * DD * D2;
            int l = j2 >> 17, off = j2 & 131071;
            int n = off >> 9, k = off & 511;      // K=512, N=256
            W2T[(size_t)l * 131072 + off] = f2bf(W2[(size_t)l * 131072 + k * DD + n]);
        }
        return;
    }
    j -= RW;
    if (j < 256) { caf[j] = 1.f; ccf[j] = 0.f; return; }
    j -= 256;
    if (j < 1024) { sums1[j] = 0.f; return; }
    j -= 1024;
    if (j < 512) { sumsF[j] = 0.f; return; }
    j -= 512;
    if (j < 256) bcnt[j] = 0;
}

// ---------------- bucketed CSR build (LDS pre-aggregated) ----------------
// A: per-block LDS histogram of coarse buckets (dst>>8), then <=196 global adds
__global__ __launch_bounds__(256)
void k_bktA(const int* __restrict__ ei, int* __restrict__ bcnt) {
    __shared__ int l[NBUCK];
    int tid = threadIdx.x;
    if (tid < NBUCK) l[tid] = 0;
    __syncthreads();
    int start = blockIdx.x * EPB;
    int end = min(start + EPB, NEDGES);
    for (int e = start + tid; e < end; e += 256)
        atomicAdd(&l[ei[e * 2 + 1] >> 8], 1);
    __syncthreads();
    if (tid < NBUCK && l[tid]) atomicAdd(&bcnt[tid], l[tid]);
}
// B: scan 196 bucket counts -> bbase (exclusive + sentinel), bcur copy
__global__ __launch_bounds__(256)
void k_bktB(const int* __restrict__ bcnt, int* __restrict__ bbase,
            int* __restrict__ bcur) {
    __shared__ int tmp[256];
    int tid = threadIdx.x;
    int v = (tid < NBUCK) ? bcnt[tid] : 0;
    tmp[tid] = v;
    __syncthreads();
    #pragma unroll
    for (int off = 1; off < 256; off <<= 1) {
        int t = (tid >= off) ? tmp[tid - off] : 0;
        __syncthreads();
        tmp[tid] += t;
        __syncthreads();
    }
    int excl = tmp[tid] - v;
    if (tid <= NBUCK) bbase[tid] = excl;
    if (tid < NBUCK) bcur[tid] = excl;
}
// C: per-block range reservation + block-local scatter of packed (src|dstlow)
__global__ __launch_bounds__(256)
void k_bktC(const int* __restrict__ ei, int* __restrict__ bcur,
            unsigned* __restrict__ ebuf) {
    __shared__ int lcnt[NBUCK];
    __shared__ int lbase[NBUCK];
    int tid = threadIdx.x;
    if (tid < NBUCK) lcnt[tid] = 0;
    __syncthreads();
    int start = blockIdx.x * EPB;
    int end = min(start + EPB, NEDGES);
    for (int e = start + tid; e < end; e += 256)
        atomicAdd(&lcnt[ei[e * 2 + 1] >> 8], 1);
    __syncthreads();
    if (tid < NBUCK) {
        int c = lcnt[tid];
        lbase[tid] = c ? atomicAdd(&bcur[tid], c) : 0;
        lcnt[tid] = 0;
    }
    __syncthreads();
    for (int e = start + tid; e < end; e += 256) {
        int src = ei[e * 2], dst = ei[e * 2 + 1];
        int b = dst >> 8;
        int off = atomicAdd(&lcnt[b], 1);
        ebuf[lbase[b] + off] = (unsigned)src | ((unsigned)(dst & 255) << 16);
    }
}
// D: per-bucket local CSR: count -> scan -> rowptr -> cursor-fill col
__global__ __launch_bounds__(256)
void k_bktD(const unsigned* __restrict__ ebuf, const int* __restrict__ bbase,
            int* __restrict__ rowptr, int* __restrict__ col) {
    __shared__ int scnt[256];
    __shared__ int sscan[256];
    int b = blockIdx.x;
    int tid = threadIdx.x;
    int s = bbase[b], e = bbase[b + 1];
    scnt[tid] = 0;
    __syncthreads();
    for (int i = s + tid; i < e; i += 256)
        atomicAdd(&scnt[ebuf[i] >> 16], 1);
    __syncthreads();
    int v = scnt[tid];
    sscan[tid] = v;
    __syncthreads();
    #pragma unroll
    for (int off = 1; off < 256; off <<= 1) {
        int t = (tid >= off) ? sscan[tid - off] : 0;
        __syncthreads();
        sscan[tid] += t;
        __syncthreads();
    }
    int excl = sscan[tid] - v;
    int gnode = b * 256 + tid;
    if (gnode <= MNODES) rowptr[gnode] = s + excl;
    __syncthreads();
    scnt[tid] = excl;          // becomes cursor
    __syncthreads();
    for (int i = s + tid; i < e; i += 256) {
        unsigned u = ebuf[i];
        int pos = s + atomicAdd(&scnt[u >> 16], 1);
        col[pos] = (int)(u & 0xFFFF) + b * 0;  // src stored in low 16? no:
    }
}

// NOTE on k_bktD col values: src is a full node id (0..49999) and does NOT fit
// in 16 bits; ebuf packs src in bits [0,16) ONLY if src < 65536 -- it is not.
// -> pack differently: ebuf = (src << 8) | (dst & 255); src<2^24, dstlow<2^8.
__global__ __launch_bounds__(256)
void k_bktC2(const int* __restrict__ ei, int* __restrict__ bcur,
             unsigned* __restrict__ ebuf) {
    __shared__ int lcnt[NBUCK];
    __shared__ int lbase[NBUCK];
    int tid = threadIdx.x;
    if (tid < NBUCK) lcnt[tid] = 0;
    __syncthreads();
    int start = blockIdx.x * EPB;
    int end = min(start + EPB, NEDGES);
    for (int e = start + tid; e < end; e += 256)
        atomicAdd(&lcnt[ei[e * 2 + 1] >> 8], 1);
    __syncthreads();
    if (tid < NBUCK) {
        int c = lcnt[tid];
        lbase[tid] = c ? atomicAdd(&bcur[tid], c) : 0;
        lcnt[tid] = 0;
    }
    __syncthreads();
    for (int e = start + tid; e < end; e += 256) {
        int src = ei[e * 2], dst = ei[e * 2 + 1];
        int b = dst >> 8;
        int off = atomicAdd(&lcnt[b], 1);
        ebuf[lbase[b] + off] = ((unsigned)src << 8) | (unsigned)(dst & 255);
    }
}
__global__ __launch_bounds__(256)
void k_bktD2(const unsigned* __restrict__ ebuf, const int* __restrict__ bbase,
             int* __restrict__ rowptr, int* __restrict__ col) {
    __shared__ int scnt[256];
    __shared__ int sscan[256];
    int b = blockIdx.x;
    int tid = threadIdx.x;
    int s = bbase[b], e = bbase[b + 1];
    scnt[tid] = 0;
    __syncthreads();
    for (int i = s + tid; i < e; i += 256)
        atomicAdd(&scnt[ebuf[i] & 255], 1);
    __syncthreads();
    int v = scnt[tid];
    sscan[tid] = v;
    __syncthreads();
    #pragma unroll
    for (int off = 1; off < 256; off <<= 1) {
        int t = (tid >= off) ? sscan[tid - off] : 0;
        __syncthreads();
        sscan[tid] += t;
        __syncthreads();
    }
    int excl = sscan[tid] - v;
    int gnode = b * 256 + tid;
    if (gnode <= MNODES) rowptr[gnode] = s + excl;
    __syncthreads();
    scnt[tid] = excl;
    __syncthreads();
    for (int i = s + tid; i < e; i += 256) {
        unsigned u = ebuf[i];
        int pos = s + atomicAdd(&scnt[u & 255], 1);
        col[pos] = (int)(u >> 8);
    }
}

// ---------------- gather: out = ca*(x[n] + sum x[src]) + (deg+1)*cc ----------
__global__ void k_gather(const int* __restrict__ rowptr, const int* __restrict__ col,
                         const ushort_t* __restrict__ x, const float* __restrict__ ca,
                         const float* __restrict__ cc, ushort_t* __restrict__ out) {
    int node = blockIdx.x * 4 + (threadIdx.x >> 6);
    int lane = threadIdx.x & 63;
    if (node >= MNODES) return;
    const ushort4* xp = (const ushort4*)x;
    ushort4 v = xp[(size_t)node * 64 + lane];
    float a0 = bf2f(v.x), a1 = bf2f(v.y), a2 = bf2f(v.z), a3 = bf2f(v.w);
    int s = rowptr[node], e = rowptr[node + 1];
    int i = s;
    for (; i + 7 < e; i += 8) {
        ushort4 u[8];
        #pragma unroll
        for (int j = 0; j < 8; j++) u[j] = xp[(size_t)col[i + j] * 64 + lane];
        #pragma unroll
        for (int j = 0; j < 8; j++) {
            a0 += bf2f(u[j].x); a1 += bf2f(u[j].y);
            a2 += bf2f(u[j].z); a3 += bf2f(u[j].w);
        }
    }
    for (; i < e; i++) {
        ushort4 u = xp[(size_t)col[i] * 64 + lane];
        a0 += bf2f(u.x); a1 += bf2f(u.y); a2 += bf2f(u.z); a3 += bf2f(u.w);
    }
    int c = lane * 4;
    float dn = (float)(e - s) + 1.0f;
    ushort4 o;
    o.x = f2bf(ca[c + 0] * a0 + dn * cc[c + 0]);
    o.y = f2bf(ca[c + 1] * a1 + dn * cc[c + 1]);
    o.z = f2bf(ca[c + 2] * a2 + dn * cc[c + 2]);
    o.w = f2bf(ca[c + 3] * a3 + dn * cc[c + 3]);
    ((ushort4*)out)[(size_t)node * 64 + lane] = o;
}

// ---------------- BN coeffs (re-zeros stats) ----------------
__global__ void k_coeffs(float* __restrict__ sums, float* __restrict__ sumsq,
                         const float* __restrict__ g, const float* __restrict__ beta,
                         float* __restrict__ ca, float* __restrict__ cc, int n) {
    int c = blockIdx.x * blockDim.x + threadIdx.x;
    if (c >= n) return;
    float mean = sums[c] * (1.0f / MNODES);
    float var  = sumsq[c] * (1.0f / MNODES) - mean * mean;
    float a    = g[c] * rsqrtf(var + BN_EPS);
    ca[c] = a;
    cc[c] = beta[c] - a * mean;
    sums[c] = 0.f;
    sumsq[c] = 0.f;
}

// ---------------- h = relu(ca*h + cc), in place, bf16, 512 cols --------------
__global__ void k_prerelu(ushort_t* __restrict__ h, const float* __restrict__ ca,
                          const float* __restrict__ cc) {
    int i = blockIdx.x * blockDim.x + threadIdx.x;
    if (i >= MNODES * (D2 / 4)) return;
    int c = (i * 4) & (D2 - 1);
    ushort4 v = ((const ushort4*)h)[i];
    ushort4 o;
    o.x = f2bf(fmaxf(ca[c + 0] * bf2f(v.x) + cc[c + 0], 0.f));
    o.y = f2bf(fmaxf(ca[c + 1] * bf2f(v.y) + cc[c + 1], 0.f));
    o.z = f2bf(fmaxf(ca[c + 2] * bf2f(v.z) + cc[c + 2], 0.f));
    o.w = f2bf(fmaxf(ca[c + 3] * bf2f(v.w) + cc[c + 3], 0.f));
    ((ushort4*)h)[i] = o;
}

// ---------------- final: d_out = ca*h + cc (fp32) ----------------
__global__ void k_apply_out(const ushort_t* __restrict__ h, const float* __restrict__ ca,
                            const float* __restrict__ cc, float* __restrict__ out) {
    int i = blockIdx.x * blockDim.x + threadIdx.x;
    if (i >= MNODES * 64) return;
    int c = (i & 63) * 4;
    ushort4 v = ((const ushort4*)h)[i];
    float4 o;
    o.x = ca[c + 0] * bf2f(v.x) + cc[c + 0];
    o.y = ca[c + 1] * bf2f(v.y) + cc[c + 1];
    o.z = ca[c + 2] * bf2f(v.z) + cc[c + 2];
    o.w = ca[c + 3] * bf2f(v.w) + cc[c + 3];
    ((float4*)out)[i] = o;
}

// ---------------- pipelined bf16 MFMA GEMM, 128x128 tile, BK=32 --------------
template<int DO_STATS, int RES>
__global__ __launch_bounds__(256, 5)
void k_gemm_bf(const ushort_t* __restrict__ A, const ushort_t* __restrict__ WT,
               const float* __restrict__ bias,
               const ushort_t* resid, const float* __restrict__ r_ca,
               const float* __restrict__ r_cc,
               ushort_t* out, float* __restrict__ sums, float* __restrict__ sumsq,
               int M, int K, int N) {
    __shared__ __align__(16) ushort_t As[2][128 * 32];
    __shared__ __align__(16) ushort_t Bs[2][128 * 32];
    const int tid = threadIdx.x;
    const int w = tid >> 6, lane = tid & 63;
    const int wm = w >> 1, wn = w & 1;
    const int quad = lane >> 4, l15 = lane & 15;
    const int m0 = blockIdx.y * 128, n0 = blockIdx.x * 128;

    const ushort_t* aA[2];
    const ushort_t* aB[2];
    int aoff[2];
    #pragma unroll
    for (int j = 0; j < 2; j++) {
        int ii = j * 4 + w;
        int r = ii * 16 + (lane >> 2);
        int cg = (lane & 3) ^ ((lane >> 3) & 3);
        aA[j] = A  + (size_t)(m0 + r) * K + cg * 8;
        aB[j] = WT + (size_t)(n0 + r) * K + cg * 8;
        aoff[j] = ii * 512;
    }

    v4f acc[4][4];
    #pragma unroll
    for (int i = 0; i < 4; i++)
        #pragma unroll
        for (int j = 0; j < 4; j++)
            acc[i][j] = (v4f){0.f, 0.f, 0.f, 0.f};

    const int nk = K >> 5;

    #pragma unroll
    for (int j = 0; j < 2; j++) {
        async16(aA[j], &As[0][aoff[j]]);
        async16(aB[j], &Bs[0][aoff[j]]);
    }
    #pragma unroll
    for (int j = 0; j < 2; j++) {
        async16(aA[j] + 32, &As[1][aoff[j]]);
        async16(aB[j] + 32, &Bs[1][aoff[j]]);
    }
    VMWAIT4();
    BARRIER();

    const int sl = quad ^ ((l15 >> 1) & 3);
    for (int t = 0; t < nk; t++) {
        const ushort_t* Ab = As[t & 1];
        const ushort_t* Bb = Bs[t & 1];
        v8bf af[4], bfr[4];
        #pragma unroll
        for (int tt = 0; tt < 4; tt++) {
            int m_l = wm * 64 + tt * 16 + l15;
            af[tt]  = *(const v8bf*)&Ab[m_l * 32 + sl * 8];
            int n_l = wn * 64 + tt * 16 + l15;
            bfr[tt] = *(const v8bf*)&Bb[n_l * 32 + sl * 8];
        }
        #pragma unroll
        for (int mt = 0; mt < 4; mt++)
            #pragma unroll
            for (int nt = 0; nt < 4; nt++)
                acc[mt][nt] = __builtin_amdgcn_mfma_f32_16x16x32_bf16(
                    af[mt], bfr[nt], acc[mt][nt], 0, 0, 0);
        if (t == nk - 1) break;
        BARRIER();
        if (t + 2 < nk) {
            int kl = (t + 2) * 32;
            #pragma unroll
            for (int j = 0; j < 2; j++) {
                async16(aA[j] + kl, &As[t & 1][aoff[j]]);
                async16(aB[j] + kl, &Bs[t & 1][aoff[j]]);
            }
            VMWAIT4();
        } else {
            VMWAIT0();
        }
        BARRIER();
    }

    const int mlim = M - m0;
    float s_sum[4] = {0.f, 0.f, 0.f, 0.f}, s_sq[4] = {0.f, 0.f, 0.f, 0.f};
    #pragma unroll
    for (int nt = 0; nt < 4; nt++) {
        int colg = n0 + wn * 64 + nt * 16 + l15;
        float bia = bias[colg];
        float rca = 0.f, rcc = 0.f;
        if (RES) { rca = r_ca[colg]; rcc = r_cc[colg]; }
        #pragma unroll
        for (int mt = 0; mt < 4; mt++) {
            int rbase = wm * 64 + mt * 16 + quad * 4;
            #pragma unroll
            for (int r = 0; r < 4; r++) {
                int rl = rbase + r;
                if (rl < mlim) {
                    size_t idx = (size_t)(m0 + rl) * N + colg;
                    float v = acc[mt][nt][r] + bia;
                    if (RES) v += rca * bf2f(resid[idx]) + rcc;
                    out[idx] = f2bf(v);
                    if (DO_STATS) { s_sum[nt] += v; s_sq[nt] += v * v; }
                }
            }
        }
    }
    if (DO_STATS) {
        #pragma unroll
        for (int nt = 0; nt < 4; nt++) {
            float s = s_sum[nt], q = s_sq[nt];
            s += __shfl_xor(s, 16); q += __shfl_xor(q, 16);
            s += __shfl_xor(s, 32); q += __shfl_xor(q, 32);
            if (quad == 0) {
                int colg = n0 + wn * 64 + nt * 16 + l15;
                atomicAdd(&sums[colg], s);
                atomicAdd(&sumsq[colg], q);
            }
        }
    }
}

extern "C" void kernel_launch(void* const* d_in, const int* in_sizes, int n_in,
                              void* d_out, int out_size, void* d_ws, size_t ws_size,
                              hipStream_t stream) {
    const float* pre   = (const float*)d_in[0];
    const int*   ei    = (const int*)d_in[1];
    const float* W0    = (const float*)d_in[2];
    const float* b0    = (const float*)d_in[3];
    const float* W1    = (const float*)d_in[4];
    const float* b1    = (const float*)d_in[5];
    const float* g1    = (const float*)d_in[6];
    const float* beta1 = (const float*)d_in[7];
    const float* W2    = (const float*)d_in[8];
    const float* b2    = (const float*)d_in[9];
    const float* gf    = (const float*)d_in[10];
    const float* betaf = (const float*)d_in[11];

    char* p = (char*)d_ws;
    ushort_t* preb = (ushort_t*)p; p += (size_t)M_PAD * DIN * 2;
    ushort_t* ACT1 = (ushort_t*)p; p += (size_t)M_PAD * DD * 2;
    ushort_t* ACT2 = (ushort_t*)p; p += (size_t)M_PAD * DD * 2;
    ushort_t* H1   = (ushort_t*)p; p += (size_t)M_PAD * D2 * 2;
    ushort_t* W0T  = (ushort_t*)p; p += (size_t)DIN * DD * 2;
    ushort_t* W1T  = (ushort_t*)p; p += (size_t)NLAYERS * DD * D2 * 2;
    ushort_t* W2T  = (ushort_t*)p; p += (size_t)NLAYERS * D2 * DD * 2;
    float* sums1  = (float*)p; p += D2 * 4;
    float* sumsq1 = (float*)p; p += D2 * 4;
    float* ca1    = (float*)p; p += D2 * 4;
    float* cc1    = (float*)p; p += D2 * 4;
    float* sumsF  = (float*)p; p += DD * 4;
    float* sumsqF = (float*)p; p += DD * 4;
    float* caf    = (float*)p; p += DD * 4;
    float* ccf    = (float*)p; p += DD * 4;
    int* bcnt   = (int*)p; p += 256 * 4;
    int* bbase  = (int*)p; p += 256 * 4;
    int* bcur   = (int*)p; p += 256 * 4;
    int* rowptr = (int*)p; p += (size_t)(MNODES + 1) * 4;
    int* colx   = (int*)p; p += (size_t)NEDGES * 4;
    unsigned* ebuf = (unsigned*)p; p += (size_t)NEDGES * 4;

    dim3 blk(256);
    const int mb = (MNODES + 127) / 128;        // 391

    const int prep_total = R0 + RW + 256 + 1024 + 512 + 256;
    k_prep_all<<<(prep_total + 255) / 256, blk, 0, stream>>>(
        pre, preb, W0, W1, W2, W0T, W1T, W2T, caf, ccf, sums1, sumsF, bcnt);

    // bucketed CSR build (LDS-aggregated)
    k_bktA<<<CSRB, blk, 0, stream>>>(ei, bcnt);
    k_bktB<<<1, blk, 0, stream>>>(bcnt, bbase, bcur);
    k_bktC2<<<CSRB, blk, 0, stream>>>(ei, bcur, ebuf);
    k_bktD2<<<NBUCK, blk, 0, stream>>>(ebuf, bbase, rowptr, colx);

    // X0 = pre @ W0 + b0  -> ACT2
    k_gemm_bf<0, 0><<<dim3(DD / 128, mb), blk, 0, stream>>>(
        preb, W0T, b0, nullptr, nullptr, nullptr,
        ACT2, nullptr, nullptr, MNODES, DIN, DD);

    for (int l = 0; l < NLAYERS; l++) {
        // ACT1 = caf*(ACT2[n] + sum ACT2[src]) + (deg+1)*ccf
        k_gather<<<(MNODES + 3) / 4, blk, 0, stream>>>(rowptr, colx, ACT2, caf, ccf, ACT1);

        // H1 = ACT1 @ W1 + b1, fused column stats
        k_gemm_bf<1, 0><<<dim3(D2 / 128, mb), blk, 0, stream>>>(
            ACT1, W1T + (size_t)l * DD * D2, b1 + (size_t)l * D2,
            nullptr, nullptr, nullptr,
            H1, sums1, sumsq1, MNODES, DD, D2);
        k_coeffs<<<2, blk, 0, stream>>>(sums1, sumsq1, g1 + (size_t)l * D2,
                                        beta1 + (size_t)l * D2, ca1, cc1, D2);

        // H1 = relu(bn1(H1)) in place
        k_prerelu<<<(MNODES * (D2 / 4) + 255) / 256, blk, 0, stream>>>(H1, ca1, cc1);

        // ACT2 = H1 @ W2 + b2 + bn_prev(ACT2)  (in place; fused stats)
        k_gemm_bf<1, 1><<<dim3(DD / 128, mb), blk, 0, stream>>>(
            H1, W2T + (size_t)l * D2 * DD, b2 + (size_t)l * DD,
            ACT2, caf, ccf,
            ACT2, sumsF, sumsqF, MNODES, D2, DD);
        k_coeffs<<<1, blk, 0, stream>>>(sumsF, sumsqF, gf + (size_t)l * DD,
                                        betaf + (size_t)l * DD, caf, ccf, DD);
    }

    // d_out = caf*ACT2 + ccf  (fp32)
    k_apply_out<<<(MNODES * 64 + 255) / 256, blk, 0, stream>>>(ACT2, caf, ccf, (float*)d_out);
}